// Round 11
// baseline (45.400 us; speedup 1.0000x reference)
//
#include <hip/hip_runtime.h>
#include <math.h>

constexpr int S    = 4096;
constexpr int L    = S - 1;       // 4095 returns
constexpr int H2   = 128;
constexpr int HID  = 256;
constexpr int NPOS = 8;           // window positions per thread (512 thr * 8 = 4096)
constexpr int WMAX = 20;
constexpr int RMAX = NPOS + WMAX - 1;  // 27 returns per thread
constexpr int ROWS = 4;           // rows per block
constexpr int NT   = 512;
constexpr float LN_EPS = 1e-5f;

constexpr int N5  = L - 5 + 1;    // 4091
constexpr int N10 = L - 10 + 1;   // 4086
constexpr int N20 = L - 20 + 1;   // 4076

__device__ __forceinline__ float fast_sqrt(float x)  { return __builtin_amdgcn_sqrtf(x); }
__device__ __forceinline__ float fast_rsqrt(float x) { return __builtin_amdgcn_rsqf(x); }

// uniform (cndmask) window sum: no divergent dual path
template<int W>
__device__ __forceinline__ float window_acc(const float (&rr)[RMAX], int t0,
                                            float s1, float s2) {
    constexpr float c1 = 1.f / (float)(W - 1);
    constexpr float c2 = 1.f / ((float)W * (float)(W - 1));
    const int n = L - W + 1;
    float acc = 0.f;
    #pragma unroll
    for (int i = 0; i < NPOS; ++i) {
        float t  = fmaf(-(s1 * c2), s1, s2 * c1);
        float sd = fast_sqrt(fmaxf(t, 0.f));
        acc += (t0 + i < n) ? sd : 0.f;          // v_cndmask, wave-uniform cost
        if (i < NPOS - 1) {
            float xin = rr[i + W], xout = rr[i];
            s1 += xin; s1 -= xout;
            s2 = fmaf(xin, xin, s2);
            s2 = fmaf(-xout, xout, s2);
        }
    }
    return acc;
}

__global__ __launch_bounds__(NT)   // no min-waves clamp (R8 spill lesson)
void vol_fused4w(const float* __restrict__ prices,
                 const float* __restrict__ W1,  const float* __restrict__ b1,
                 const float* __restrict__ g1,  const float* __restrict__ be1,
                 const float* __restrict__ W2,  const float* __restrict__ b2,
                 const float* __restrict__ g2,  const float* __restrict__ be2,
                 const float* __restrict__ Wc1, const float* __restrict__ bc1,
                 const float* __restrict__ Wc2, const float* __restrict__ bc2,
                 float* __restrict__ out_combined, float* __restrict__ out_regime)
{
    __shared__ __align__(16) float lp[S + 28];   // 16.5 KB; aliased by MLP scratch
    __shared__ float redw[ROWS][8][3];           // per-wave partials (vol; reused for LN)
    __shared__ float vols_sh[ROWS][4];

    // MLP scratch aliases lp (dead after vol loop):
    float* fbuf  = lp;                 // comb: fbuf[row*HID + idx], 1024 floats (4 KB)
    float* partb = lp + 1024;          // 2048 floats (8 KB), byte off 4096 (16B aligned)

    const int tid = threadIdx.x;
    const int w   = tid >> 6;          // wave 0..7
    const int r0  = blockIdx.x * ROWS;

    if (tid < 7) *reinterpret_cast<float4*>(&lp[S + 0]) = make_float4(0,0,0,0),
                 lp[S + 4 * tid + 0] = 0.f, lp[S + 4 * tid + 1] = 0.f,
                 lp[S + 4 * tid + 2] = 0.f, lp[S + 4 * tid + 3] = 0.f;

    // prefetch row 0 (coalesced float4: 1024 slots / 512 thr = 2 each)
    const float4* prow = reinterpret_cast<const float4*>(prices + (size_t)r0 * S);
    float4 pf0 = prow[tid], pf1 = prow[tid + NT];

    // ================= vol loop: 4 rows sequentially =================
    #pragma unroll 1
    for (int r = 0; r < ROWS; ++r) {
        float4 nf0, nf1;
        if (r < ROWS - 1) {            // issue next-row loads before compute
            const float4* nrow =
                reinterpret_cast<const float4*>(prices + (size_t)(r0 + r + 1) * S);
            nf0 = nrow[tid]; nf1 = nrow[tid + NT];
        }
        {   // log(current row) -> LDS
            float4 o;
            o.x = __logf(fmaxf(pf0.x, 1e-8f)); o.y = __logf(fmaxf(pf0.y, 1e-8f));
            o.z = __logf(fmaxf(pf0.z, 1e-8f)); o.w = __logf(fmaxf(pf0.w, 1e-8f));
            *reinterpret_cast<float4*>(&lp[(tid) * 4]) = o;
            o.x = __logf(fmaxf(pf1.x, 1e-8f)); o.y = __logf(fmaxf(pf1.y, 1e-8f));
            o.z = __logf(fmaxf(pf1.z, 1e-8f)); o.w = __logf(fmaxf(pf1.w, 1e-8f));
            *reinterpret_cast<float4*>(&lp[(tid + NT) * 4]) = o;
        }
        __syncthreads();

        const int t0 = tid * NPOS;
        float lpv[28];                 // 7 float4 LDS reads
        #pragma unroll
        for (int j = 0; j < 7; ++j) {
            float4 v = *reinterpret_cast<const float4*>(&lp[t0 + 4 * j]);
            lpv[4 * j + 0] = v.x; lpv[4 * j + 1] = v.y;
            lpv[4 * j + 2] = v.z; lpv[4 * j + 3] = v.w;
        }
        float rr[RMAX];
        #pragma unroll
        for (int i = 0; i < RMAX; ++i) rr[i] = lpv[i + 1] - lpv[i];

        float s1a = 0.f, s2a = 0.f;
        #pragma unroll
        for (int j = 0; j < 5; ++j)  { s1a += rr[j]; s2a = fmaf(rr[j], rr[j], s2a); }
        float s1b = s1a, s2b = s2a;
        #pragma unroll
        for (int j = 5; j < 10; ++j) { s1b += rr[j]; s2b = fmaf(rr[j], rr[j], s2b); }
        float s1c = s1b, s2c = s2b;
        #pragma unroll
        for (int j = 10; j < 20; ++j){ s1c += rr[j]; s2c = fmaf(rr[j], rr[j], s2c); }

        float sum5  = window_acc<5>(rr, t0, s1a, s2a);
        float sum10 = window_acc<10>(rr, t0, s1b, s2b);
        float sum20 = window_acc<20>(rr, t0, s1c, s2c);

        #pragma unroll
        for (int off = 32; off; off >>= 1) {
            sum5  += __shfl_down(sum5,  off);
            sum10 += __shfl_down(sum10, off);
            sum20 += __shfl_down(sum20, off);
        }
        if ((tid & 63) == 0) {
            redw[r][w][0] = sum5; redw[r][w][1] = sum10; redw[r][w][2] = sum20;
        }
        __syncthreads();   // lp reads done -> safe to overwrite
        if (r < ROWS - 1) { pf0 = nf0; pf1 = nf1; }
    }
    if (tid < ROWS * 3) {
        int r = tid / 3, k = tid % 3;
        constexpr float sc[3] = { 1.f / N5, 1.f / N10, 1.f / N20 };
        float s = 0.f;
        #pragma unroll
        for (int ww = 0; ww < 8; ++ww) s += redw[r][ww][k];
        vols_sh[r][k] = s * sc[k];
    }
    __syncthreads();

    // ================= MLP for 4 rows =================
    const int c  = tid & 127;      // column
    const int rw = tid >> 7;       // row 0..3
    // ---- layer 1 + LN (512 threads = 4 rows x 128 cols) ----
    float x = fmaxf(fmaf(vols_sh[rw][2], W1[2 * H2 + c],
                    fmaf(vols_sh[rw][1], W1[H2 + c],
                    fmaf(vols_sh[rw][0], W1[c], b1[c]))), 0.f);
    {
        float s = x, sq = x * x;
        #pragma unroll
        for (int off = 32; off; off >>= 1) { s += __shfl_down(s, off); sq += __shfl_down(sq, off); }
        if ((tid & 63) == 0) { redw[0][w][0] = s; redw[0][w][1] = sq; }
    }
    __syncthreads();
    {
        float ss = redw[0][rw * 2][0] + redw[0][rw * 2 + 1][0];
        float sq = redw[0][rw * 2][1] + redw[0][rw * 2 + 1][1];
        float mu = ss * (1.f / H2);
        float var = sq * (1.f / H2) - mu * mu;
        float rs = fast_rsqrt(fmaxf(var, 0.f) + LN_EPS);
        fbuf[rw * HID + c] = (x - mu) * rs * g1[c] + be1[c];
    }
    __syncthreads();

    // ---- layer 2 (128x128), 4-row weight-stationary:
    //      tid = row + 4*kq + 16*q  (row 0..3, kq 0..3 -> 32 k-elems, q 0..31 col-quad)
    //      adjacent lanes (rows) share each weight float4 -> L1 broadcast
    {
        const int row = tid & 3, kq = (tid >> 2) & 3, q = tid >> 4;
        const float* wb  = W2 + (size_t)(kq * 32) * H2 + q * 4;
        const float* ap  = &fbuf[row * HID + kq * 32];
        float ax = 0.f, ay = 0.f, az = 0.f, aw = 0.f;
        #pragma unroll 8
        for (int k = 0; k < 32; ++k) {
            float a = ap[k];
            float4 ww = *reinterpret_cast<const float4*>(wb + (size_t)k * H2);
            ax = fmaf(a, ww.x, ax); ay = fmaf(a, ww.y, ay);
            az = fmaf(a, ww.z, az); aw = fmaf(a, ww.w, aw);
        }
        // partb[kq][row][q] float4
        reinterpret_cast<float4*>(partb)[(kq * 4 + row) * 32 + q] =
            make_float4(ax, ay, az, aw);
    }
    __syncthreads();
    float x2;
    {
        const int qq = c >> 2, ci = c & 3;
        float ss = partb[((0 * 4 + rw) * 32 + qq) * 4 + ci] +
                   partb[((1 * 4 + rw) * 32 + qq) * 4 + ci] +
                   partb[((2 * 4 + rw) * 32 + qq) * 4 + ci] +
                   partb[((3 * 4 + rw) * 32 + qq) * 4 + ci];
        x2 = fmaxf(ss + b2[c], 0.f);
    }
    {
        float s = x2, sq = x2 * x2;
        #pragma unroll
        for (int off = 32; off; off >>= 1) { s += __shfl_down(s, off); sq += __shfl_down(sq, off); }
        if ((tid & 63) == 0) { redw[0][w][0] = s; redw[0][w][1] = sq; }
    }
    __syncthreads();
    {
        float ss = redw[0][rw * 2][0] + redw[0][rw * 2 + 1][0];
        float sq = redw[0][rw * 2][1] + redw[0][rw * 2 + 1][1];
        float mu = ss * (1.f / H2);
        float var = sq * (1.f / H2) - mu * mu;
        float rs = fast_rsqrt(fmaxf(var, 0.f) + LN_EPS);
        fbuf[rw * HID + H2 + c] = (x2 - mu) * rs * g2[c] + be2[c];
    }
    __syncthreads();

    // ---- classifier 256->64, 4-row weight-stationary:
    //      tid = row + 4*kq + 32*cq (row 0..3, kq 0..7 -> 32 k-elems, cq 0..15 col-quad)
    {
        const int row = tid & 3, kq = (tid >> 2) & 7, cq = tid >> 5;
        const float* wb = Wc1 + (size_t)(kq * 32) * 64 + cq * 4;
        const float* ap = &fbuf[row * HID + kq * 32];
        float ax = 0.f, ay = 0.f, az = 0.f, aw = 0.f;
        #pragma unroll 8
        for (int k = 0; k < 32; ++k) {
            float a = ap[k];
            float4 ww = *reinterpret_cast<const float4*>(wb + (size_t)k * 64);
            ax = fmaf(a, ww.x, ax); ay = fmaf(a, ww.y, ay);
            az = fmaf(a, ww.z, az); aw = fmaf(a, ww.w, aw);
        }
        // partb[kq][row][cq] float4
        reinterpret_cast<float4*>(partb)[(kq * 4 + row) * 16 + cq] =
            make_float4(ax, ay, az, aw);
    }
    __syncthreads();

    // ---- combine + logits + softmax (4 waves; wave r handles row r) ----
    if (tid < 256) {
        const int r = tid >> 6, cc = tid & 63;
        const int cq = cc >> 2, ci = cc & 3;
        float ss = 0.f;
        #pragma unroll
        for (int kq = 0; kq < 8; ++kq)
            ss += partb[((kq * 4 + r) * 16 + cq) * 4 + ci];
        float c1v = fmaxf(ss + bc1[cc], 0.f);
        float4 wrow = reinterpret_cast<const float4*>(Wc2)[cc];   // Wc2[cc][0..3]
        float lx = c1v * wrow.x, ly = c1v * wrow.y, lz = c1v * wrow.z, lw = c1v * wrow.w;
        #pragma unroll
        for (int off = 32; off; off >>= 1) {
            lx += __shfl_down(lx, off);
            ly += __shfl_down(ly, off);
            lz += __shfl_down(lz, off);
            lw += __shfl_down(lw, off);
        }
        if (cc == 0) {
            float4 bb = *reinterpret_cast<const float4*>(bc2);
            float l0 = lx + bb.x, l1 = ly + bb.y, l2 = lz + bb.z, l3 = lw + bb.w;
            float m  = fmaxf(fmaxf(l0, l1), fmaxf(l2, l3));
            float e0 = __expf(l0 - m), e1 = __expf(l1 - m);
            float e2 = __expf(l2 - m), e3 = __expf(l3 - m);
            float inv = 1.f / (e0 + e1 + e2 + e3);
            reinterpret_cast<float4*>(out_regime)[r0 + r] =
                make_float4(e0 * inv, e1 * inv, e2 * inv, e3 * inv);
        }
    }

    // ---- write combined (4 rows x 64 float4) ----
    if (tid < 256) {
        const int r = tid >> 6, c4 = tid & 63;
        float4 vv = *reinterpret_cast<const float4*>(&fbuf[r * HID + c4 * 4]);
        reinterpret_cast<float4*>(out_combined)[(size_t)(r0 + r) * 64 + c4] = vv;
    }
}

extern "C" void kernel_launch(void* const* d_in, const int* in_sizes, int n_in,
                              void* d_out, int out_size, void* d_ws, size_t ws_size,
                              hipStream_t stream) {
    const float* prices = (const float*)d_in[0];
    const float* W1  = (const float*)d_in[1];
    const float* b1  = (const float*)d_in[2];
    const float* g1  = (const float*)d_in[3];
    const float* be1 = (const float*)d_in[4];
    const float* W2  = (const float*)d_in[5];
    const float* b2  = (const float*)d_in[6];
    const float* g2  = (const float*)d_in[7];
    const float* be2 = (const float*)d_in[8];
    const float* Wc1 = (const float*)d_in[9];
    const float* bc1 = (const float*)d_in[10];
    const float* Wc2 = (const float*)d_in[11];
    const float* bc2 = (const float*)d_in[12];

    const int B = in_sizes[0] / S;                 // 4096
    float* out_combined = (float*)d_out;
    float* out_regime   = (float*)d_out + (size_t)B * HID;

    vol_fused4w<<<B / ROWS, NT, 0, stream>>>(prices, W1, b1, g1, be1, W2, b2, g2, be2,
                                             Wc1, bc1, Wc2, bc2, out_combined, out_regime);
}

// Round 12
// 41.102 us; speedup vs baseline: 1.1046x; 1.1046x over previous
//
#include <hip/hip_runtime.h>
#include <math.h>

constexpr int S    = 4096;
constexpr int L    = S - 1;        // 4095 returns
constexpr int H2   = 128;
constexpr int HID  = 256;
constexpr int NPOS = 8;            // positions per thread per chunk
constexpr int WMAX = 20;
constexpr int RMAX = NPOS + WMAX - 1;   // 27
constexpr int ROWS = 2;
constexpr int NT   = 256;
constexpr int CH   = 2048;         // chunk size (floats)
constexpr int CHS  = CH / 4;       // 512 float4 slots per chunk
constexpr int CBF  = CH + 40;      // buffer floats (chunk + 36 overlap + pad)
constexpr float LN_EPS = 1e-5f;

constexpr int N5  = L - 5 + 1;     // 4091
constexpr int N10 = L - 10 + 1;    // 4086
constexpr int N20 = L - 20 + 1;    // 4076

__device__ __forceinline__ float fast_sqrt(float x)  { return __builtin_amdgcn_sqrtf(x); }
__device__ __forceinline__ float fast_rsqrt(float x) { return __builtin_amdgcn_rsqf(x); }

__device__ __forceinline__ float4 log4(float4 v) {
    return make_float4(__logf(fmaxf(v.x, 1e-8f)), __logf(fmaxf(v.y, 1e-8f)),
                       __logf(fmaxf(v.z, 1e-8f)), __logf(fmaxf(v.w, 1e-8f)));
}

template<int W>
__device__ __forceinline__ float window_acc(const float (&rr)[RMAX], int t0,
                                            float s1, float s2) {
    constexpr float c1 = 1.f / (float)(W - 1);
    constexpr float c2 = 1.f / ((float)W * (float)(W - 1));
    const int n = L - W + 1;
    float acc = 0.f;
    if (t0 + NPOS <= n) {            // fast path (all positions valid)
        #pragma unroll
        for (int i = 0; i < NPOS; ++i) {
            float t = fmaf(-(s1 * c2), s1, s2 * c1);
            acc += fast_sqrt(fmaxf(t, 0.f));
            if (i < NPOS - 1) {
                float xin = rr[i + W], xout = rr[i];
                s1 += xin; s1 -= xout;
                s2 = fmaf(xin, xin, s2);
                s2 = fmaf(-xout, xout, s2);
            }
        }
    } else {                          // boundary path (tail threads of chunk 1)
        #pragma unroll
        for (int i = 0; i < NPOS; ++i) {
            float t  = fmaf(-(s1 * c2), s1, s2 * c1);
            float sd = fast_sqrt(fmaxf(t, 0.f));
            if (t0 + i < n) acc += sd;
            if (i < NPOS - 1) {
                float xin = rr[i + W], xout = rr[i];
                s1 += xin; s1 -= xout;
                s2 = fmaf(xin, xin, s2);
                s2 = fmaf(-xout, xout, s2);
            }
        }
    }
    return acc;
}

__global__ __launch_bounds__(NT)     // no min-waves clamp (R8 spill lesson)
void vol_chunk(const float* __restrict__ prices,
               const float* __restrict__ W1,  const float* __restrict__ b1,
               const float* __restrict__ g1,  const float* __restrict__ be1,
               const float* __restrict__ W2,  const float* __restrict__ b2,
               const float* __restrict__ g2,  const float* __restrict__ be2,
               const float* __restrict__ Wc1, const float* __restrict__ bc1,
               const float* __restrict__ Wc2, const float* __restrict__ bc2,
               float* __restrict__ out_combined, float* __restrict__ out_regime)
{
    __shared__ __align__(16) float lp[CBF];     // 8.35 KB chunk buffer; MLP scratch aliases
    __shared__ float redw[ROWS][4][3];
    __shared__ float vols_sh[ROWS][4];

    float* fbuf  = lp;                  // 512 floats  (MLP h|h2f per row)
    float* partb = lp + 512;            // 1024 floats (GEMV partials), 2048B offset

    const int tid = threadIdx.x;
    const int w   = tid >> 6;
    const int r0  = blockIdx.x * ROWS;

    // ---- prologue: stage row 0 chunk 0 ----
    {
        const float4* p = reinterpret_cast<const float4*>(prices + (size_t)r0 * S);
        float4 s0 = p[tid], s1 = p[256 + tid];
        *reinterpret_cast<float4*>(&lp[tid * 4])         = log4(s0);
        *reinterpret_cast<float4*>(&lp[(256 + tid) * 4]) = log4(s1);
        if (tid < 9) {
            float4 sb = p[512 + tid];                    // in-row (slots 512..520)
            *reinterpret_cast<float4*>(&lp[(512 + tid) * 4]) = log4(sb);
        }
    }
    __syncthreads();

    // ---- vol loop: ROWS rows x 2 chunks through the single 8.4 KB buffer ----
    #pragma unroll 1
    for (int r = 0; r < ROWS; ++r) {
        float sum5 = 0.f, sum10 = 0.f, sum20 = 0.f;
        #pragma unroll 1
        for (int ch = 0; ch < 2; ++ch) {
            const bool hasnext = !(r == ROWS - 1 && ch == 1);
            float4 n0, n1, nb;
            if (hasnext) {                   // issue next-chunk loads before compute
                const int nr  = (ch == 0) ? r : r + 1;
                const int nch = (ch == 0) ? 1 : 0;
                const float4* p = reinterpret_cast<const float4*>(prices + (size_t)(r0 + nr) * S);
                const int base = nch * CHS;
                n0 = p[base + tid]; n1 = p[base + 256 + tid];
                if (tid < 9) {
                    int sl = base + 512 + tid; sl = sl < 1024 ? sl : 1023;   // clamp at row end
                    nb = p[sl];
                }
            }

            // compute current chunk from LDS
            {
                float lpv[RMAX + 1];         // 28 floats = 7 float4 reads
                #pragma unroll
                for (int j = 0; j < 7; ++j) {
                    float4 v = *reinterpret_cast<const float4*>(&lp[tid * NPOS + 4 * j]);
                    lpv[4 * j + 0] = v.x; lpv[4 * j + 1] = v.y;
                    lpv[4 * j + 2] = v.z; lpv[4 * j + 3] = v.w;
                }
                float rr[RMAX];
                #pragma unroll
                for (int i = 0; i < RMAX; ++i) rr[i] = lpv[i + 1] - lpv[i];

                float s1a = 0.f, s2a = 0.f;
                #pragma unroll
                for (int j = 0; j < 5; ++j)  { s1a += rr[j]; s2a = fmaf(rr[j], rr[j], s2a); }
                float s1b = s1a, s2b = s2a;
                #pragma unroll
                for (int j = 5; j < 10; ++j) { s1b += rr[j]; s2b = fmaf(rr[j], rr[j], s2b); }
                float s1c = s1b, s2c = s2b;
                #pragma unroll
                for (int j = 10; j < 20; ++j){ s1c += rr[j]; s2c = fmaf(rr[j], rr[j], s2c); }

                const int t0g = ch * CH + tid * NPOS;
                sum5  += window_acc<5>(rr, t0g, s1a, s2a);
                sum10 += window_acc<10>(rr, t0g, s1b, s2b);
                sum20 += window_acc<20>(rr, t0g, s1c, s2c);
            }

            if (ch == 1) {                   // row done: wave-reduce the 3 sums
                #pragma unroll
                for (int off = 32; off; off >>= 1) {
                    sum5  += __shfl_down(sum5,  off);
                    sum10 += __shfl_down(sum10, off);
                    sum20 += __shfl_down(sum20, off);
                }
                if ((tid & 63) == 0) {
                    redw[r][w][0] = sum5; redw[r][w][1] = sum10; redw[r][w][2] = sum20;
                }
            }
            __syncthreads();                 // all reads of lp done (+ redw visible)

            if (hasnext) {                   // overwrite buffer with next chunk's logs
                *reinterpret_cast<float4*>(&lp[tid * 4])         = log4(n0);
                *reinterpret_cast<float4*>(&lp[(256 + tid) * 4]) = log4(n1);
                if (tid < 9)
                    *reinterpret_cast<float4*>(&lp[(512 + tid) * 4]) = log4(nb);
                __syncthreads();             // writes done before next compute
            }
        }
    }
    if (tid < ROWS * 3) {
        int r = tid / 3, k = tid % 3;
        constexpr float sc[3] = { 1.f / N5, 1.f / N10, 1.f / N20 };
        vols_sh[r][k] = (redw[r][0][k] + redw[r][1][k] + redw[r][2][k] + redw[r][3][k]) * sc[k];
    }
    __syncthreads();

    // ================= MLP for 2 rows (R8's proven layout) =================
    const int c  = tid & 127;
    const int rw = tid >> 7;
    // ---- layer 1 + LN ----
    float x = fmaxf(fmaf(vols_sh[rw][2], W1[2 * H2 + c],
                    fmaf(vols_sh[rw][1], W1[H2 + c],
                    fmaf(vols_sh[rw][0], W1[c], b1[c]))), 0.f);
    {
        float s = x, sq = x * x;
        #pragma unroll
        for (int off = 32; off; off >>= 1) { s += __shfl_down(s, off); sq += __shfl_down(sq, off); }
        if ((tid & 63) == 0) { redw[0][w][0] = s; redw[0][w][1] = sq; }
    }
    __syncthreads();
    {
        float ss = redw[0][rw * 2][0] + redw[0][rw * 2 + 1][0];
        float sq = redw[0][rw * 2][1] + redw[0][rw * 2 + 1][1];
        float mu = ss * (1.f / H2);
        float var = sq * (1.f / H2) - mu * mu;
        float rs = fast_rsqrt(fmaxf(var, 0.f) + LN_EPS);
        fbuf[rw * HID + c] = (x - mu) * rs * g1[c] + be1[c];
    }
    __syncthreads();

    // ---- layer 2 (128x128): q=tid&31 col-quad, r2=(tid>>5)&1 row, kq=tid>>6 ----
    {
        const int q = tid & 31, r2 = (tid >> 5) & 1, kq = tid >> 6;
        const float* wb = W2 + (size_t)(kq * 32) * H2 + q * 4;
        const float* ab = &fbuf[r2 * HID + kq * 32];
        float ax = 0.f, ay = 0.f, az = 0.f, aw = 0.f;
        #pragma unroll 8
        for (int k = 0; k < 32; ++k) {
            float a = ab[k];
            float4 ww = *reinterpret_cast<const float4*>(wb + (size_t)k * H2);
            ax = fmaf(a, ww.x, ax); ay = fmaf(a, ww.y, ay);
            az = fmaf(a, ww.z, az); aw = fmaf(a, ww.w, aw);
        }
        reinterpret_cast<float4*>(partb)[tid] = make_float4(ax, ay, az, aw); // [kq][r2][q]
    }
    __syncthreads();
    float x2;
    {
        const int qq = c >> 2, ci = c & 3;
        float ss = partb[(0 * 64 + rw * 32 + qq) * 4 + ci] +
                   partb[(1 * 64 + rw * 32 + qq) * 4 + ci] +
                   partb[(2 * 64 + rw * 32 + qq) * 4 + ci] +
                   partb[(3 * 64 + rw * 32 + qq) * 4 + ci];
        x2 = fmaxf(ss + b2[c], 0.f);
    }
    {
        float s = x2, sq = x2 * x2;
        #pragma unroll
        for (int off = 32; off; off >>= 1) { s += __shfl_down(s, off); sq += __shfl_down(sq, off); }
        if ((tid & 63) == 0) { redw[0][w][0] = s; redw[0][w][1] = sq; }
    }
    __syncthreads();
    {
        float ss = redw[0][rw * 2][0] + redw[0][rw * 2 + 1][0];
        float sq = redw[0][rw * 2][1] + redw[0][rw * 2 + 1][1];
        float mu = ss * (1.f / H2);
        float var = sq * (1.f / H2) - mu * mu;
        float rs = fast_rsqrt(fmaxf(var, 0.f) + LN_EPS);
        fbuf[rw * HID + H2 + c] = (x2 - mu) * rs * g2[c] + be2[c];
    }
    __syncthreads();

    // ---- classifier 256->64: cq=tid&15, r2=(tid>>4)&1, kq=tid>>5 ----
    {
        const int cq = tid & 15, r2 = (tid >> 4) & 1, kq = tid >> 5;
        const float* wb = Wc1 + (size_t)(kq * 32) * 64 + cq * 4;
        const float* ab = &fbuf[r2 * HID + kq * 32];
        float ax = 0.f, ay = 0.f, az = 0.f, aw = 0.f;
        #pragma unroll 8
        for (int k = 0; k < 32; ++k) {
            float a = ab[k];
            float4 ww = *reinterpret_cast<const float4*>(wb + (size_t)k * 64);
            ax = fmaf(a, ww.x, ax); ay = fmaf(a, ww.y, ay);
            az = fmaf(a, ww.z, az); aw = fmaf(a, ww.w, aw);
        }
        reinterpret_cast<float4*>(partb)[tid] = make_float4(ax, ay, az, aw); // [kq][r2][cq]
    }
    __syncthreads();

    // ---- combine + logits + softmax (2 waves; wave r handles row r) ----
    if (tid < 128) {
        const int r = tid >> 6, cc = tid & 63;
        const int cq = cc >> 2, ci = cc & 3;
        float ss = 0.f;
        #pragma unroll
        for (int kq = 0; kq < 8; ++kq)
            ss += partb[(kq * 32 + r * 16 + cq) * 4 + ci];
        float c1v = fmaxf(ss + bc1[cc], 0.f);
        float4 wrow = reinterpret_cast<const float4*>(Wc2)[cc];   // Wc2[cc][0..3]
        float lx = c1v * wrow.x, ly = c1v * wrow.y, lz = c1v * wrow.z, lw = c1v * wrow.w;
        #pragma unroll
        for (int off = 32; off; off >>= 1) {
            lx += __shfl_down(lx, off);
            ly += __shfl_down(ly, off);
            lz += __shfl_down(lz, off);
            lw += __shfl_down(lw, off);
        }
        if (cc == 0) {
            float4 bb = *reinterpret_cast<const float4*>(bc2);
            float l0 = lx + bb.x, l1 = ly + bb.y, l2 = lz + bb.z, l3 = lw + bb.w;
            float m  = fmaxf(fmaxf(l0, l1), fmaxf(l2, l3));
            float e0 = __expf(l0 - m), e1 = __expf(l1 - m);
            float e2 = __expf(l2 - m), e3 = __expf(l3 - m);
            float inv = 1.f / (e0 + e1 + e2 + e3);
            reinterpret_cast<float4*>(out_regime)[r0 + r] =
                make_float4(e0 * inv, e1 * inv, e2 * inv, e3 * inv);
        }
    }

    // ---- write combined ----
    if (tid < 128) {
        const int r = tid >> 6, c4 = tid & 63;
        float4 vv = *reinterpret_cast<const float4*>(&fbuf[r * HID + c4 * 4]);
        reinterpret_cast<float4*>(out_combined)[(size_t)(r0 + r) * 64 + c4] = vv;
    }
}

extern "C" void kernel_launch(void* const* d_in, const int* in_sizes, int n_in,
                              void* d_out, int out_size, void* d_ws, size_t ws_size,
                              hipStream_t stream) {
    const float* prices = (const float*)d_in[0];
    const float* W1  = (const float*)d_in[1];
    const float* b1  = (const float*)d_in[2];
    const float* g1  = (const float*)d_in[3];
    const float* be1 = (const float*)d_in[4];
    const float* W2  = (const float*)d_in[5];
    const float* b2  = (const float*)d_in[6];
    const float* g2  = (const float*)d_in[7];
    const float* be2 = (const float*)d_in[8];
    const float* Wc1 = (const float*)d_in[9];
    const float* bc1 = (const float*)d_in[10];
    const float* Wc2 = (const float*)d_in[11];
    const float* bc2 = (const float*)d_in[12];

    const int B = in_sizes[0] / S;                 // 4096
    float* out_combined = (float*)d_out;
    float* out_regime   = (float*)d_out + (size_t)B * HID;

    vol_chunk<<<B / ROWS, NT, 0, stream>>>(prices, W1, b1, g1, be1, W2, b2, g2, be2,
                                           Wc1, bc1, Wc2, bc2, out_combined, out_regime);
}

// Round 13
// 39.151 us; speedup vs baseline: 1.1596x; 1.0499x over previous
//
#include <hip/hip_runtime.h>
#include <math.h>

constexpr int S    = 4096;
constexpr int L    = S - 1;        // 4095 returns
constexpr int H2   = 128;
constexpr int HID  = 256;
constexpr int NPOS = 8;            // positions per thread per chunk
constexpr int WMAX = 20;
constexpr int RMAX = NPOS + WMAX - 1;   // 27
constexpr int ROWS = 2;
constexpr int NT   = 256;
constexpr int CH   = 2048;         // chunk size (floats)
constexpr int CHS  = CH / 4;       // 512 float4 slots per chunk
constexpr int LPF  = 2560;         // lp floats: max(vol 2088, MLP 512+2048)
constexpr float LN_EPS = 1e-5f;

constexpr int N5  = L - 5 + 1;     // 4091
constexpr int N10 = L - 10 + 1;    // 4086
constexpr int N20 = L - 20 + 1;    // 4076

__device__ __forceinline__ float fast_sqrt(float x)  { return __builtin_amdgcn_sqrtf(x); }
__device__ __forceinline__ float fast_rsqrt(float x) { return __builtin_amdgcn_rsqf(x); }

__device__ __forceinline__ float4 log4(float4 v) {
    return make_float4(__logf(fmaxf(v.x, 1e-8f)), __logf(fmaxf(v.y, 1e-8f)),
                       __logf(fmaxf(v.z, 1e-8f)), __logf(fmaxf(v.w, 1e-8f)));
}

// accumulates sqrt(W*s2 - s1^2); caller folds 1/sqrt(W*(W-1)) into the mean scale
template<int W>
__device__ __forceinline__ float window_acc(const float (&rr)[RMAX], int t0,
                                            float s1, float s2) {
    constexpr float Wf = (float)W;
    const int n = L - W + 1;
    float acc = 0.f;
    if (t0 + NPOS <= n) {            // fast path
        #pragma unroll
        for (int i = 0; i < NPOS; ++i) {
            float t = fmaf(Wf, s2, -(s1 * s1));
            acc += fast_sqrt(fmaxf(t, 0.f));
            if (i < NPOS - 1) {
                float xin = rr[i + W], xout = rr[i];
                s1 += xin; s1 -= xout;
                s2 = fmaf(xin, xin, s2);
                s2 = fmaf(-xout, xout, s2);
            }
        }
    } else {                          // boundary path (tail threads of chunk 1)
        #pragma unroll
        for (int i = 0; i < NPOS; ++i) {
            float t  = fmaf(Wf, s2, -(s1 * s1));
            float sd = fast_sqrt(fmaxf(t, 0.f));
            if (t0 + i < n) acc += sd;
            if (i < NPOS - 1) {
                float xin = rr[i + W], xout = rr[i];
                s1 += xin; s1 -= xout;
                s2 = fmaf(xin, xin, s2);
                s2 = fmaf(-xout, xout, s2);
            }
        }
    }
    return acc;
}

__global__ __launch_bounds__(NT)     // no min-waves clamp (R8 spill lesson)
void vol_ws(const float* __restrict__ prices,
            const float* __restrict__ W1,  const float* __restrict__ b1,
            const float* __restrict__ g1,  const float* __restrict__ be1,
            const float* __restrict__ W2,  const float* __restrict__ b2,
            const float* __restrict__ g2,  const float* __restrict__ be2,
            const float* __restrict__ Wc1, const float* __restrict__ bc1,
            const float* __restrict__ Wc2, const float* __restrict__ bc2,
            float* __restrict__ out_combined, float* __restrict__ out_regime)
{
    __shared__ __align__(16) float lp[LPF];   // 10.24 KB; vol chunk buffer / MLP scratch
    __shared__ float redw[ROWS][4][3];
    __shared__ float vols_sh[ROWS][4];

    float* fbuf  = lp;                  // 512 floats  (MLP h|h2f per row)
    float* partb = lp + 512;            // 2048 floats (weight-stationary partials)

    const int tid = threadIdx.x;
    const int w   = tid >> 6;
    const int r0  = blockIdx.x * ROWS;

    // ---- prologue: stage row 0 chunk 0 ----
    {
        const float4* p = reinterpret_cast<const float4*>(prices + (size_t)r0 * S);
        float4 s0 = p[tid], s1 = p[256 + tid];
        *reinterpret_cast<float4*>(&lp[tid * 4])         = log4(s0);
        *reinterpret_cast<float4*>(&lp[(256 + tid) * 4]) = log4(s1);
        if (tid < 9) {
            float4 sb = p[512 + tid];
            *reinterpret_cast<float4*>(&lp[(512 + tid) * 4]) = log4(sb);
        }
    }
    __syncthreads();

    // ---- vol loop: ROWS rows x 2 chunks through the single buffer ----
    #pragma unroll 1
    for (int r = 0; r < ROWS; ++r) {
        float sum5 = 0.f, sum10 = 0.f, sum20 = 0.f;
        #pragma unroll 1
        for (int ch = 0; ch < 2; ++ch) {
            const bool hasnext = !(r == ROWS - 1 && ch == 1);
            float4 n0, n1, nb;
            if (hasnext) {                   // issue next-chunk loads before compute
                const int nr  = (ch == 0) ? r : r + 1;
                const int nch = (ch == 0) ? 1 : 0;
                const float4* p = reinterpret_cast<const float4*>(prices + (size_t)(r0 + nr) * S);
                const int base = nch * CHS;
                n0 = p[base + tid]; n1 = p[base + 256 + tid];
                if (tid < 9) {
                    int sl = base + 512 + tid; sl = sl < 1024 ? sl : 1023;
                    nb = p[sl];
                }
            }

            // compute current chunk from LDS
            {
                float lpv[RMAX + 1];         // 28 floats = 7 float4 reads
                #pragma unroll
                for (int j = 0; j < 7; ++j) {
                    float4 v = *reinterpret_cast<const float4*>(&lp[tid * NPOS + 4 * j]);
                    lpv[4 * j + 0] = v.x; lpv[4 * j + 1] = v.y;
                    lpv[4 * j + 2] = v.z; lpv[4 * j + 3] = v.w;
                }
                float rr[RMAX];
                #pragma unroll
                for (int i = 0; i < RMAX; ++i) rr[i] = lpv[i + 1] - lpv[i];

                float s1a = 0.f, s2a = 0.f;
                #pragma unroll
                for (int j = 0; j < 5; ++j)  { s1a += rr[j]; s2a = fmaf(rr[j], rr[j], s2a); }
                float s1b = s1a, s2b = s2a;
                #pragma unroll
                for (int j = 5; j < 10; ++j) { s1b += rr[j]; s2b = fmaf(rr[j], rr[j], s2b); }
                float s1c = s1b, s2c = s2b;
                #pragma unroll
                for (int j = 10; j < 20; ++j){ s1c += rr[j]; s2c = fmaf(rr[j], rr[j], s2c); }

                const int t0g = ch * CH + tid * NPOS;
                sum5  += window_acc<5>(rr, t0g, s1a, s2a);
                sum10 += window_acc<10>(rr, t0g, s1b, s2b);
                sum20 += window_acc<20>(rr, t0g, s1c, s2c);
            }

            if (ch == 1) {                   // row done: wave-reduce the 3 sums
                #pragma unroll
                for (int off = 32; off; off >>= 1) {
                    sum5  += __shfl_down(sum5,  off);
                    sum10 += __shfl_down(sum10, off);
                    sum20 += __shfl_down(sum20, off);
                }
                if ((tid & 63) == 0) {
                    redw[r][w][0] = sum5; redw[r][w][1] = sum10; redw[r][w][2] = sum20;
                }
            }
            __syncthreads();                 // all reads of lp done (+ redw visible)

            if (hasnext) {                   // overwrite buffer with next chunk's logs
                *reinterpret_cast<float4*>(&lp[tid * 4])         = log4(n0);
                *reinterpret_cast<float4*>(&lp[(256 + tid) * 4]) = log4(n1);
                if (tid < 9)
                    *reinterpret_cast<float4*>(&lp[(512 + tid) * 4]) = log4(nb);
                __syncthreads();
            }
        }
    }
    if (tid < ROWS * 3) {
        int r = tid / 3, k = tid % 3;
        // mean scale with hoisted 1/sqrt(W*(W-1)):
        // sqrt(20)=4.472135955, sqrt(90)=9.4868329805, sqrt(380)=19.4935886896
        constexpr float sc[3] = { 1.f / (N5  * 4.47213595499958f),
                                  1.f / (N10 * 9.48683298050514f),
                                  1.f / (N20 * 19.4935886896179f) };
        vols_sh[r][k] = (redw[r][0][k] + redw[r][1][k] + redw[r][2][k] + redw[r][3][k]) * sc[k];
    }
    __syncthreads();

    // ================= MLP for 2 rows (R10 weight-stationary) =================
    const int c  = tid & 127;
    const int rw = tid >> 7;
    // ---- layer 1 + LN ----
    float x = fmaxf(fmaf(vols_sh[rw][2], W1[2 * H2 + c],
                    fmaf(vols_sh[rw][1], W1[H2 + c],
                    fmaf(vols_sh[rw][0], W1[c], b1[c]))), 0.f);
    {
        float s = x, sq = x * x;
        #pragma unroll
        for (int off = 32; off; off >>= 1) { s += __shfl_down(s, off); sq += __shfl_down(sq, off); }
        if ((tid & 63) == 0) { redw[0][w][0] = s; redw[0][w][1] = sq; }
    }
    __syncthreads();
    {
        float ss = redw[0][rw * 2][0] + redw[0][rw * 2 + 1][0];
        float sq = redw[0][rw * 2][1] + redw[0][rw * 2 + 1][1];
        float mu = ss * (1.f / H2);
        float var = sq * (1.f / H2) - mu * mu;
        float rs = fast_rsqrt(fmaxf(var, 0.f) + LN_EPS);
        fbuf[rw * HID + c] = (x - mu) * rs * g1[c] + be1[c];
    }
    __syncthreads();

    // ---- layer 2 (128x128), weight-stationary: q=tid&31 col-quad, kq=tid>>5 (8 k-segs) ----
    {
        const int q = tid & 31, kq = tid >> 5;
        const float* wb = W2 + (size_t)(kq * 16) * H2 + q * 4;
        const float* a0p = &fbuf[kq * 16];            // row 0 h
        const float* a1p = &fbuf[HID + kq * 16];      // row 1 h
        float r0x = 0.f, r0y = 0.f, r0z = 0.f, r0w = 0.f;
        float r1x = 0.f, r1y = 0.f, r1z = 0.f, r1w = 0.f;
        #pragma unroll
        for (int k = 0; k < 16; ++k) {
            float4 ww = *reinterpret_cast<const float4*>(wb + (size_t)k * H2);
            float a0 = a0p[k], a1 = a1p[k];
            r0x = fmaf(a0, ww.x, r0x); r0y = fmaf(a0, ww.y, r0y);
            r0z = fmaf(a0, ww.z, r0z); r0w = fmaf(a0, ww.w, r0w);
            r1x = fmaf(a1, ww.x, r1x); r1y = fmaf(a1, ww.y, r1y);
            r1z = fmaf(a1, ww.z, r1z); r1w = fmaf(a1, ww.w, r1w);
        }
        float4* p4 = reinterpret_cast<float4*>(partb);
        p4[kq * 32 + q]       = make_float4(r0x, r0y, r0z, r0w);   // row0 [kq][q]
        p4[256 + kq * 32 + q] = make_float4(r1x, r1y, r1z, r1w);   // row1
    }
    __syncthreads();
    float x2;
    {
        const int qq = c >> 2, ci = c & 3;
        const float* pb = partb + rw * 1024;
        float ss = 0.f;
        #pragma unroll
        for (int kq = 0; kq < 8; ++kq) ss += pb[(kq * 32 + qq) * 4 + ci];
        x2 = fmaxf(ss + b2[c], 0.f);
    }
    {
        float s = x2, sq = x2 * x2;
        #pragma unroll
        for (int off = 32; off; off >>= 1) { s += __shfl_down(s, off); sq += __shfl_down(sq, off); }
        if ((tid & 63) == 0) { redw[0][w][0] = s; redw[0][w][1] = sq; }
    }
    __syncthreads();
    {
        float ss = redw[0][rw * 2][0] + redw[0][rw * 2 + 1][0];
        float sq = redw[0][rw * 2][1] + redw[0][rw * 2 + 1][1];
        float mu = ss * (1.f / H2);
        float var = sq * (1.f / H2) - mu * mu;
        float rs = fast_rsqrt(fmaxf(var, 0.f) + LN_EPS);
        fbuf[rw * HID + H2 + c] = (x2 - mu) * rs * g2[c] + be2[c];
    }
    __syncthreads();

    // ---- classifier 256->64, weight-stationary: cq=tid&15, kq=tid>>4 (16 k-segs) ----
    {
        const int cq = tid & 15, kq = tid >> 4;
        const float* wb = Wc1 + (size_t)(kq * 16) * 64 + cq * 4;
        const float* a0p = &fbuf[kq * 16];            // row 0 comb
        const float* a1p = &fbuf[HID + kq * 16];      // row 1 comb
        float r0x = 0.f, r0y = 0.f, r0z = 0.f, r0w = 0.f;
        float r1x = 0.f, r1y = 0.f, r1z = 0.f, r1w = 0.f;
        #pragma unroll
        for (int k = 0; k < 16; ++k) {
            float4 ww = *reinterpret_cast<const float4*>(wb + (size_t)k * 64);
            float a0 = a0p[k], a1 = a1p[k];
            r0x = fmaf(a0, ww.x, r0x); r0y = fmaf(a0, ww.y, r0y);
            r0z = fmaf(a0, ww.z, r0z); r0w = fmaf(a0, ww.w, r0w);
            r1x = fmaf(a1, ww.x, r1x); r1y = fmaf(a1, ww.y, r1y);
            r1z = fmaf(a1, ww.z, r1z); r1w = fmaf(a1, ww.w, r1w);
        }
        float4* p4 = reinterpret_cast<float4*>(partb);
        p4[kq * 16 + cq]       = make_float4(r0x, r0y, r0z, r0w);  // row0 [kq][cq]
        p4[256 + kq * 16 + cq] = make_float4(r1x, r1y, r1z, r1w);  // row1
    }
    __syncthreads();

    // ---- combine + logits + softmax (2 waves; wave r handles row r) ----
    if (tid < 128) {
        const int r = tid >> 6, cc = tid & 63;
        const int cq = cc >> 2, ci = cc & 3;
        const float* pb = partb + r * 1024;
        float ss = 0.f;
        #pragma unroll
        for (int kq = 0; kq < 16; ++kq) ss += pb[(kq * 16 + cq) * 4 + ci];
        float c1v = fmaxf(ss + bc1[cc], 0.f);
        float4 wrow = reinterpret_cast<const float4*>(Wc2)[cc];   // Wc2[cc][0..3]
        float lx = c1v * wrow.x, ly = c1v * wrow.y, lz = c1v * wrow.z, lw = c1v * wrow.w;
        #pragma unroll
        for (int off = 32; off; off >>= 1) {
            lx += __shfl_down(lx, off);
            ly += __shfl_down(ly, off);
            lz += __shfl_down(lz, off);
            lw += __shfl_down(lw, off);
        }
        if (cc == 0) {
            float4 bb = *reinterpret_cast<const float4*>(bc2);
            float l0 = lx + bb.x, l1 = ly + bb.y, l2 = lz + bb.z, l3 = lw + bb.w;
            float m  = fmaxf(fmaxf(l0, l1), fmaxf(l2, l3));
            float e0 = __expf(l0 - m), e1 = __expf(l1 - m);
            float e2 = __expf(l2 - m), e3 = __expf(l3 - m);
            float inv = 1.f / (e0 + e1 + e2 + e3);
            reinterpret_cast<float4*>(out_regime)[r0 + r] =
                make_float4(e0 * inv, e1 * inv, e2 * inv, e3 * inv);
        }
    }

    // ---- write combined ----
    if (tid < 128) {
        const int r = tid >> 6, c4 = tid & 63;
        float4 vv = *reinterpret_cast<const float4*>(&fbuf[r * HID + c4 * 4]);
        reinterpret_cast<float4*>(out_combined)[(size_t)(r0 + r) * 64 + c4] = vv;
    }
}

extern "C" void kernel_launch(void* const* d_in, const int* in_sizes, int n_in,
                              void* d_out, int out_size, void* d_ws, size_t ws_size,
                              hipStream_t stream) {
    const float* prices = (const float*)d_in[0];
    const float* W1  = (const float*)d_in[1];
    const float* b1  = (const float*)d_in[2];
    const float* g1  = (const float*)d_in[3];
    const float* be1 = (const float*)d_in[4];
    const float* W2  = (const float*)d_in[5];
    const float* b2  = (const float*)d_in[6];
    const float* g2  = (const float*)d_in[7];
    const float* be2 = (const float*)d_in[8];
    const float* Wc1 = (const float*)d_in[9];
    const float* bc1 = (const float*)d_in[10];
    const float* Wc2 = (const float*)d_in[11];
    const float* bc2 = (const float*)d_in[12];

    const int B = in_sizes[0] / S;                 // 4096
    float* out_combined = (float*)d_out;
    float* out_regime   = (float*)d_out + (size_t)B * HID;

    vol_ws<<<B / ROWS, NT, 0, stream>>>(prices, W1, b1, g1, be1, W2, b2, g2, be2,
                                        Wc1, bc1, Wc2, bc2, out_combined, out_regime);
}